// Round 6
// baseline (365.097 us; speedup 1.0000x reference)
//
#include <hip/hip_runtime.h>
#include <hip/hip_bf16.h>

#define NCH 64
#define HIST_BLOCKS 256
#define HIST_THREADS 1024
#define NSCAT 256          // scatter blocks (fused kernel, low half)
#define NGEMM 768          // gemm blocks   (fused kernel, high half)
#define FUSE_THREADS 512   // 8 waves/block

// ---------------------------------------------------------------------------
// Block 0: dtype detection (flags[0]=fp32?, flags[1]=int64?).
// Other blocks: zero the per-node degree array (ws is poisoned each call).
// ---------------------------------------------------------------------------
__global__ void detect_init_kernel(const unsigned short* __restrict__ gp, int n16,
                                   const unsigned* __restrict__ ip, int niw,
                                   unsigned* __restrict__ flags,
                                   unsigned* __restrict__ deg, int n_nodes) {
    if (blockIdx.x == 0) {
        __shared__ unsigned se, so;
        if (threadIdx.x == 0) { se = 0u; so = 0u; }
        __syncthreads();
        unsigned le = 0u, lo = 0u;
        // fp32 viewed as shorts: ~12.5% show "bf16 exponent" >= 0xC0 (|x|>=2^65).
        // Genuine bf16 N(0,1): none.
        for (int i = threadIdx.x; i < n16; i += blockDim.x) {
            unsigned ex = (unsigned)((gp[i] >> 7) & 0xFFu);
            if (ex >= 0xC0u) le++;
        }
        // int64 ids (<2^31): every odd 32-bit word is 0. int32 ids: not.
        for (int i = threadIdx.x; i < niw; i += blockDim.x) {
            if ((i & 1) && ip[i] != 0u) lo++;
        }
        atomicAdd(&se, le);
        atomicAdd(&so, lo);
        __syncthreads();
        if (threadIdx.x == 0) {
            flags[0] = (se > 50u) ? 1u : 0u;
            flags[1] = (so < 50u) ? 1u : 0u;
        }
    } else {
        const int stride = (gridDim.x - 1) * blockDim.x;
        for (int i = (blockIdx.x - 1) * blockDim.x + threadIdx.x; i < n_nodes;
             i += stride)
            deg[i] = 0u;
    }
}

// ---------------------------------------------------------------------------
// Per-NODE degree histogram via direct global atomics (50k counters can't fit
// LDS; ~16 edges/node -> low contention; atomics are device-scope/TCC-side).
// Round-5 restructure: the whole 64-node bucket layer existed only to enable
// LDS staging; direct per-node counting sort removes one full pass.
// ---------------------------------------------------------------------------
__global__ void deg_hist_kernel(const void* __restrict__ dstp,
                                unsigned* __restrict__ deg,
                                const unsigned* __restrict__ flags, int n_edges) {
    const unsigned i64 = flags[1];
    const int stride = gridDim.x * blockDim.x;
    for (int e = blockIdx.x * blockDim.x + threadIdx.x; e < n_edges; e += stride) {
        int d = i64 ? (int)((const long long*)dstp)[e] : ((const int*)dstp)[e];
        atomicAdd(&deg[d], 1u);
    }
}

// ---------------------------------------------------------------------------
// Exclusive scan over n_nodes degrees -> offs (CSR) + cursor. One block,
// 1024 threads, L=ceil(N/1024) serial elements per thread.
// ---------------------------------------------------------------------------
__global__ void node_scan_kernel(const unsigned* __restrict__ deg,
                                 unsigned* __restrict__ offs,
                                 unsigned* __restrict__ cursor,
                                 int n_nodes, int n_edges) {
    __shared__ unsigned s[1024];
    const int t = threadIdx.x;
    const int L = (n_nodes + 1023) / 1024;
    unsigned local = 0u;
    for (int i = 0; i < L; ++i) {
        int idx = t * L + i;
        if (idx < n_nodes) local += deg[idx];
    }
    s[t] = local;
    __syncthreads();
    for (int off = 1; off < 1024; off <<= 1) {
        unsigned v = (t >= off) ? s[t - off] : 0u;
        __syncthreads();
        s[t] += v;
        __syncthreads();
    }
    unsigned run = s[t] - local;
    for (int i = 0; i < L; ++i) {
        int idx = t * L + i;
        if (idx < n_nodes) { offs[idx] = run; cursor[idx] = run; run += deg[idx]; }
    }
    if (t == 0) offs[n_nodes] = (unsigned)n_edges;
}

// ---------------------------------------------------------------------------
// FUSED kernel. Blocks [0,NSCAT): direct scatter — counting-sort placement of
// src ids into per-node CSR runs (pos = atomicAdd(cursor[d])). No LDS, no
// staging, no packed format, no bucket_sort pass. Blocks [NSCAT,NSCAT+NGEMM):
// edge-MLP GEMM (P = G@W^T; Q' = RSC@W^T - b), spatially overlapped.
// __launch_bounds__(512,4): round-4 lesson — (512,8) forced VGPR 52->32 and
// spilled the per-lane w[64] array to scratch (FETCH 16->321 MB, 48->131us).
// ---------------------------------------------------------------------------
__global__ __launch_bounds__(FUSE_THREADS, 4)
void scatter_gemm_kernel(const void* __restrict__ srcp, const void* __restrict__ dstp,
                         unsigned* __restrict__ cursor,
                         unsigned* __restrict__ sorted_src,
                         const unsigned* __restrict__ flags, int n_edges,
                         const void* __restrict__ Gp, const void* __restrict__ Rp,
                         const void* __restrict__ Wp, const void* __restrict__ bp,
                         void* __restrict__ PQ, int n_nodes) {
    extern __shared__ unsigned lds[];
    if (blockIdx.x < NSCAT) {
        // ------------------------- scatter path ---------------------------
        const unsigned i64 = flags[1];
        const int chunk = (n_edges + NSCAT - 1) / NSCAT;
        const int e0 = blockIdx.x * chunk;
        const int e1 = min(e0 + chunk, n_edges);
        for (int e = e0 + threadIdx.x; e < e1; e += blockDim.x) {
            int s, d;
            if (i64) {
                s = (int)((const long long*)srcp)[e];
                d = (int)((const long long*)dstp)[e];
            } else {
                s = ((const int*)srcp)[e];
                d = ((const int*)dstp)[e];
            }
            const unsigned pos = atomicAdd(&cursor[d], 1u);
            sorted_src[pos] = (unsigned)s;
        }
    } else {
        // -------------------------- gemm path -----------------------------
        const unsigned f32 = flags[0];
        const int lane = threadIdx.x & 63;
        const int waveInBlk = threadIdx.x >> 6;
        const int wavesPerBlk = blockDim.x >> 6;          // 8
        const int gwave = (blockIdx.x - NSCAT) * wavesPerBlk + waveInBlk;
        const int nwaves = NGEMM * wavesPerBlk;
        const int n_rows = 2 * n_nodes;
        const int ngroups = (n_rows + 3) / 4;

        float* ldsb = (float*)lds;                        // 8KB dyn LDS
        float* slot = &ldsb[waveInBlk * 4 * NCH];

        float w[NCH];
        float bias;
        if (f32) {
            const float* Wf = (const float*)Wp;
            #pragma unroll
            for (int k = 0; k < NCH; ++k) w[k] = Wf[lane * NCH + k];
            bias = ((const float*)bp)[lane];
        } else {
            const __hip_bfloat16* Wh = (const __hip_bfloat16*)Wp;
            #pragma unroll
            for (int k = 0; k < NCH; ++k) w[k] = __bfloat162float(Wh[lane * NCH + k]);
            bias = __bfloat162float(((const __hip_bfloat16*)bp)[lane]);
        }

        const int niter = (ngroups + nwaves - 1) / nwaves;
        for (int it = 0; it < niter; ++it) {
            const int grp = gwave + it * nwaves;
            const bool gvalid = (grp < ngroups);
            const int m0 = grp * 4;
            if (gvalid) {
                const int myrow = m0 + (lane >> 4);
                const int col = (lane & 15) * 4;
                float x0 = 0.f, x1 = 0.f, x2 = 0.f, x3 = 0.f;
                if (myrow < n_rows) {
                    const bool isQ = (myrow >= n_nodes);
                    const int r = isQ ? (myrow - n_nodes) : myrow;
                    const void* inp = isQ ? Rp : Gp;
                    if (f32) {
                        float4 v = *(const float4*)((const float*)inp +
                                                    (size_t)r * NCH + col);
                        x0 = v.x; x1 = v.y; x2 = v.z; x3 = v.w;
                    } else {
                        ushort4 v = *(const ushort4*)((const unsigned short*)inp +
                                                      (size_t)r * NCH + col);
                        x0 = __bfloat162float(*(__hip_bfloat16*)&v.x);
                        x1 = __bfloat162float(*(__hip_bfloat16*)&v.y);
                        x2 = __bfloat162float(*(__hip_bfloat16*)&v.z);
                        x3 = __bfloat162float(*(__hip_bfloat16*)&v.w);
                    }
                }
                const int sb = (lane >> 4) * NCH + col;
                slot[sb + 0] = x0; slot[sb + 1] = x1;
                slot[sb + 2] = x2; slot[sb + 3] = x3;
            }
            __syncthreads();
            if (gvalid) {
                #pragma unroll
                for (int rr = 0; rr < 4; ++rr) {
                    const int m = m0 + rr;
                    if (m < n_rows) {
                        float a0 = 0.f, a1 = 0.f, a2 = 0.f, a3 = 0.f;
                        const float4* r4 = (const float4*)(slot + rr * NCH);
                        #pragma unroll
                        for (int q = 0; q < 16; ++q) {
                            float4 rv = r4[q];
                            a0 = fmaf(rv.x, w[4 * q + 0], a0);
                            a1 = fmaf(rv.y, w[4 * q + 1], a1);
                            a2 = fmaf(rv.z, w[4 * q + 2], a2);
                            a3 = fmaf(rv.w, w[4 * q + 3], a3);
                        }
                        float acc = (a0 + a1) + (a2 + a3);
                        if (m >= n_nodes) acc -= bias;       // Q' = RSC@W^T - b
                        if (f32) ((float*)PQ)[(size_t)m * NCH + lane] = acc;
                        else ((__hip_bfloat16*)PQ)[(size_t)m * NCH + lane] =
                                 __float2bfloat16(acc);
                    }
                }
            }
            __syncthreads();
        }
    }
}

// ---------------------------------------------------------------------------
// One wave per node, HALF-WAVE SPLIT: lanes 0-31 process even-indexed edges,
// lanes 32-63 odd-indexed; each lane covers 2 channels via float2/ushort2.
// (Measured neutral vs scalar layout in round 5 — kept, not worth churn.)
// Register-lean, no LDS -> full occupancy for gather-latency hiding.
// ---------------------------------------------------------------------------
__global__ __launch_bounds__(256)
void node_kernel(const void* __restrict__ PQ,
                 const unsigned* __restrict__ sorted_src,
                 const unsigned* __restrict__ offs,
                 const unsigned* __restrict__ flags,
                 void* __restrict__ outp, int n_nodes) {
    const unsigned f32 = flags[0];
    const int lane = threadIdx.x & 63;
    const int h = lane >> 5;            // half-wave id: edge parity
    const int c2 = lane & 31;           // channel pair -> channels 2c2, 2c2+1
    const int gwave = (blockIdx.x * blockDim.x + threadIdx.x) >> 6;
    const int nwaves = (gridDim.x * blockDim.x) >> 6;
    const float* Pf = (const float*)PQ;
    const unsigned short* Ph = (const unsigned short*)PQ;

    for (int n = gwave; n < n_nodes; n += nwaves) {
        float q0, q1;
        if (f32) {
            float2 qq = *(const float2*)&Pf[(size_t)(n_nodes + n) * NCH + 2 * c2];
            q0 = qq.x; q1 = qq.y;
        } else {
            ushort2 qq = *(const ushort2*)&Ph[(size_t)(n_nodes + n) * NCH + 2 * c2];
            q0 = __bfloat162float(*(__hip_bfloat16*)&qq.x);
            q1 = __bfloat162float(*(__hip_bfloat16*)&qq.y);
        }
        const int start = (int)offs[n];
        const int end = (int)offs[n + 1];
        float m0 = 0.f, m1 = 0.f, s0 = 0.f, s1 = 0.f;
        int j = start;
        for (; j + 8 <= end; j += 8) {
            const int i0 = j + h;                    // this half's 4 edges
            const int e0 = (int)sorted_src[i0];
            const int e1 = (int)sorted_src[i0 + 2];
            const int e2 = (int)sorted_src[i0 + 4];
            const int e3 = (int)sorted_src[i0 + 6];
            float p00, p01, p10, p11, p20, p21, p30, p31;
            if (f32) {
                float2 v0 = *(const float2*)&Pf[(size_t)e0 * NCH + 2 * c2];
                float2 v1 = *(const float2*)&Pf[(size_t)e1 * NCH + 2 * c2];
                float2 v2 = *(const float2*)&Pf[(size_t)e2 * NCH + 2 * c2];
                float2 v3 = *(const float2*)&Pf[(size_t)e3 * NCH + 2 * c2];
                p00 = v0.x; p01 = v0.y; p10 = v1.x; p11 = v1.y;
                p20 = v2.x; p21 = v2.y; p30 = v3.x; p31 = v3.y;
            } else {
                ushort2 u0 = *(const ushort2*)&Ph[(size_t)e0 * NCH + 2 * c2];
                ushort2 u1 = *(const ushort2*)&Ph[(size_t)e1 * NCH + 2 * c2];
                ushort2 u2 = *(const ushort2*)&Ph[(size_t)e2 * NCH + 2 * c2];
                ushort2 u3 = *(const ushort2*)&Ph[(size_t)e3 * NCH + 2 * c2];
                p00 = __bfloat162float(*(__hip_bfloat16*)&u0.x);
                p01 = __bfloat162float(*(__hip_bfloat16*)&u0.y);
                p10 = __bfloat162float(*(__hip_bfloat16*)&u1.x);
                p11 = __bfloat162float(*(__hip_bfloat16*)&u1.y);
                p20 = __bfloat162float(*(__hip_bfloat16*)&u2.x);
                p21 = __bfloat162float(*(__hip_bfloat16*)&u2.y);
                p30 = __bfloat162float(*(__hip_bfloat16*)&u3.x);
                p31 = __bfloat162float(*(__hip_bfloat16*)&u3.y);
            }
            const float v00 = fmaxf(p00 - q0, 0.f), v01 = fmaxf(p01 - q1, 0.f);
            const float v10 = fmaxf(p10 - q0, 0.f), v11 = fmaxf(p11 - q1, 0.f);
            const float v20 = fmaxf(p20 - q0, 0.f), v21 = fmaxf(p21 - q1, 0.f);
            const float v30 = fmaxf(p30 - q0, 0.f), v31 = fmaxf(p31 - q1, 0.f);
            m0 = fmaxf(fmaxf(m0, v00), fmaxf(v10, fmaxf(v20, v30)));
            m1 = fmaxf(fmaxf(m1, v01), fmaxf(v11, fmaxf(v21, v31)));
            s0 += (v00 + v10) + (v20 + v30);
            s1 += (v01 + v11) + (v21 + v31);
        }
        // tail: up to 7 remaining edges, parity-assigned to halves
        #pragma unroll
        for (int u = 0; u < 4; ++u) {
            const int idx = j + 2 * u + h;
            if (idx < end) {
                const int e = (int)sorted_src[idx];
                float p0, p1;
                if (f32) {
                    float2 v = *(const float2*)&Pf[(size_t)e * NCH + 2 * c2];
                    p0 = v.x; p1 = v.y;
                } else {
                    ushort2 uu = *(const ushort2*)&Ph[(size_t)e * NCH + 2 * c2];
                    p0 = __bfloat162float(*(__hip_bfloat16*)&uu.x);
                    p1 = __bfloat162float(*(__hip_bfloat16*)&uu.y);
                }
                const float v0 = fmaxf(p0 - q0, 0.f);
                const float v1 = fmaxf(p1 - q1, 0.f);
                m0 = fmaxf(m0, v0); m1 = fmaxf(m1, v1);
                s0 += v0; s1 += v1;
            }
        }
        // combine the two halves (lane l <-> l^32)
        m0 = fmaxf(m0, __shfl_xor(m0, 32));
        m1 = fmaxf(m1, __shfl_xor(m1, 32));
        s0 = s0 + __shfl_xor(s0, 32);
        s1 = s1 + __shfl_xor(s1, 32);
        const int deg = end - start;
        const float inv = 1.0f / (float)(deg > 0 ? deg : 1);
        const float a0 = s0 * inv, a1 = s1 * inv;
        if (h == 0) {
            if (f32) {
                float* out = (float*)outp;
                *(float2*)&out[(size_t)n * 2 * NCH + 2 * c2] = make_float2(m0, m1);
                *(float2*)&out[(size_t)n * 2 * NCH + NCH + 2 * c2] = make_float2(a0, a1);
            } else {
                unsigned short* out = (unsigned short*)outp;
                __hip_bfloat16 hm0 = __float2bfloat16(m0);
                __hip_bfloat16 hm1 = __float2bfloat16(m1);
                __hip_bfloat16 ha0 = __float2bfloat16(a0);
                __hip_bfloat16 ha1 = __float2bfloat16(a1);
                ushort2 sm, sa;
                sm.x = *(unsigned short*)&hm0; sm.y = *(unsigned short*)&hm1;
                sa.x = *(unsigned short*)&ha0; sa.y = *(unsigned short*)&ha1;
                *(ushort2*)&out[(size_t)n * 2 * NCH + 2 * c2] = sm;
                *(ushort2*)&out[(size_t)n * 2 * NCH + NCH + 2 * c2] = sa;
            }
        }
    }
}

extern "C" void kernel_launch(void* const* d_in, const int* in_sizes, int n_in,
                              void* d_out, int out_size, void* d_ws, size_t ws_size,
                              hipStream_t stream) {
    const void* G = d_in[0];
    const void* RSC = d_in[1];
    const void* src = d_in[2];
    const void* dst = d_in[3];
    const void* W = d_in[4];
    const void* b = d_in[5];

    const int n_nodes = in_sizes[0] / NCH;
    const int n_edges = in_sizes[2];

    // ws layout (bytes): [flags 256][sorted 4E][offs 4(N+1)][cursor 4N]
    //                    [deg 4N][PQ dtype*64*2N]
    char* ws = (char*)d_ws;
    unsigned* flags = (unsigned*)ws;
    size_t off = 256;
    unsigned* sorted_src = (unsigned*)(ws + off);
    off += (((size_t)n_edges * 4 + 255) / 256) * 256;
    unsigned* offs = (unsigned*)(ws + off);
    off += (((size_t)(n_nodes + 1) * 4 + 255) / 256) * 256;
    unsigned* cursor = (unsigned*)(ws + off);
    off += (((size_t)n_nodes * 4 + 255) / 256) * 256;
    unsigned* deg = (unsigned*)(ws + off);
    off += (((size_t)n_nodes * 4 + 255) / 256) * 256;
    void* PQ = (void*)(ws + off);                   // fp32 or bf16 per flags[0]

    const int n_g_probe = (in_sizes[0] < 8192) ? in_sizes[0] : 8192;
    const int n_idx_probe = (n_edges < 8192) ? n_edges : 8192;

    detect_init_kernel<<<64, 256, 0, stream>>>((const unsigned short*)G, n_g_probe,
                                               (const unsigned*)src, n_idx_probe,
                                               flags, deg, n_nodes);

    deg_hist_kernel<<<HIST_BLOCKS, HIST_THREADS, 0, stream>>>(dst, deg, flags,
                                                              n_edges);

    node_scan_kernel<<<1, 1024, 0, stream>>>(deg, offs, cursor, n_nodes, n_edges);

    const size_t gemm_lds = (size_t)(FUSE_THREADS / 64) * 4 * NCH * 4;  // 8 KB
    scatter_gemm_kernel<<<NSCAT + NGEMM, FUSE_THREADS, gemm_lds, stream>>>(
        src, dst, cursor, sorted_src, flags, n_edges,
        G, RSC, W, b, PQ, n_nodes);

    node_kernel<<<2048, 256, 0, stream>>>(PQ, sorted_src, offs, flags, d_out, n_nodes);
}

// Round 7
// 184.259 us; speedup vs baseline: 1.9814x; 1.9814x over previous
//
#include <hip/hip_runtime.h>
#include <hip/hip_bf16.h>

#define NCH 64
#define SPAN 64            // dst nodes per bucket (dl fits in 6 bits)
#define HIST_BLOCKS 256
#define HIST_THREADS 1024
#define NBIN 256           // binning blocks (fused kernel, low half)
#define NGEMM 768          // gemm blocks   (fused kernel, high half)
#define FUSE_THREADS 512   // 8 waves/block
#define NB_CAP 1536        // staged edges per bucket in bucket_node (lambda~1024)

// ---------------------------------------------------------------------------
// Block 0: dtype detection (flags[0]=fp32?, flags[1]=int64?).
// Other blocks: zero the bucket-count array (ws is poisoned 0xAA each call).
// ---------------------------------------------------------------------------
__global__ void detect_init_kernel(const unsigned short* __restrict__ gp, int n16,
                                   const unsigned* __restrict__ ip, int niw,
                                   unsigned* __restrict__ flags,
                                   unsigned* __restrict__ gcnt, int nb) {
    if (blockIdx.x == 0) {
        __shared__ unsigned se, so;
        if (threadIdx.x == 0) { se = 0u; so = 0u; }
        __syncthreads();
        unsigned le = 0u, lo = 0u;
        // fp32 viewed as shorts: ~12.5% show "bf16 exponent" >= 0xC0 (|x|>=2^65).
        // Genuine bf16 N(0,1): none.
        for (int i = threadIdx.x; i < n16; i += blockDim.x) {
            unsigned ex = (unsigned)((gp[i] >> 7) & 0xFFu);
            if (ex >= 0xC0u) le++;
        }
        // int64 ids (<2^31): every odd 32-bit word is 0. int32 ids: not.
        for (int i = threadIdx.x; i < niw; i += blockDim.x) {
            if ((i & 1) && ip[i] != 0u) lo++;
        }
        atomicAdd(&se, le);
        atomicAdd(&so, lo);
        __syncthreads();
        if (threadIdx.x == 0) {
            flags[0] = (se > 50u) ? 1u : 0u;
            flags[1] = (so < 50u) ? 1u : 0u;
        }
    } else {
        const int stride = (gridDim.x - 1) * blockDim.x;
        for (int i = (blockIdx.x - 1) * blockDim.x + threadIdx.x; i < nb; i += stride)
            gcnt[i] = 0u;
    }
}

// ---------------------------------------------------------------------------
// Bucket histogram: LDS pre-aggregation (nb counters), one global atomic per
// bucket per block. (Round-6 lesson: per-node direct global atomics lose.)
// ---------------------------------------------------------------------------
__global__ void bucket_hist_kernel(const void* __restrict__ dstp,
                                   unsigned* __restrict__ gcnt,
                                   const unsigned* __restrict__ flags,
                                   int n_edges, int nb) {
    extern __shared__ unsigned lcnt[];
    for (int i = threadIdx.x; i < nb; i += blockDim.x) lcnt[i] = 0u;
    __syncthreads();
    const unsigned i64 = flags[1];
    const int stride = gridDim.x * blockDim.x;
    for (int e = blockIdx.x * blockDim.x + threadIdx.x; e < n_edges; e += stride) {
        int d = i64 ? (int)((const long long*)dstp)[e] : ((const int*)dstp)[e];
        atomicAdd(&lcnt[d >> 6], 1u);
    }
    __syncthreads();
    for (int i = threadIdx.x; i < nb; i += blockDim.x)
        if (lcnt[i]) atomicAdd(&gcnt[i], lcnt[i]);
}

// ---------------------------------------------------------------------------
// Exclusive scan over nb (~782) bucket counts -> boffs (stable) + cursor.
// L=1 per thread at nb<=1024 — fast (round-6 lesson: 50k-wide scan in one
// block is 127us; bucket-granular scan is ~3us).
// ---------------------------------------------------------------------------
__global__ void bucket_scan_kernel(const unsigned* __restrict__ gcnt,
                                   unsigned* __restrict__ boffs,
                                   unsigned* __restrict__ cursor, int nb) {
    __shared__ unsigned s[1024];
    const int t = threadIdx.x;
    const int L = (nb + 1023) / 1024;
    unsigned local = 0u;
    for (int i = 0; i < L; ++i) {
        int idx = t * L + i;
        if (idx < nb) local += gcnt[idx];
    }
    s[t] = local;
    __syncthreads();
    for (int off = 1; off < 1024; off <<= 1) {
        unsigned v = (t >= off) ? s[t - off] : 0u;
        __syncthreads();
        s[t] += v;
        __syncthreads();
    }
    unsigned run = s[t] - local;
    for (int i = 0; i < L; ++i) {
        int idx = t * L + i;
        if (idx < nb) { boffs[idx] = run; cursor[idx] = run; run += gcnt[idx]; }
    }
}

// ---------------------------------------------------------------------------
// FUSED kernel. Blocks [0,NBIN): binning (LDS-staged scatter of packed
// dl|src into bucket-grouped order). Blocks [NBIN,NBIN+NGEMM): edge-MLP GEMM
// (P = G@W^T; Q' = RSC@W^T - b), spatially overlapped.
// __launch_bounds__(512,4): round-4 lesson — (512,8) forced VGPR 52->32 and
// spilled the per-lane w[64] array to scratch (FETCH 16->321 MB, 48->131us).
// ---------------------------------------------------------------------------
__global__ __launch_bounds__(FUSE_THREADS, 4)
void binning_gemm_kernel(const void* __restrict__ srcp, const void* __restrict__ dstp,
                         unsigned* __restrict__ cursor, unsigned* __restrict__ binned,
                         const unsigned* __restrict__ flags, int n_edges, int nb,
                         int depth,
                         const void* __restrict__ Gp, const void* __restrict__ Rp,
                         const void* __restrict__ Wp, const void* __restrict__ bp,
                         void* __restrict__ PQ, int n_nodes) {
    extern __shared__ unsigned lds[];
    if (blockIdx.x < NBIN) {
        // ------------------------- binning path ---------------------------
        unsigned* lcnt = lds;               // [nb]
        unsigned* stage = lds + nb;         // [nb*depth]
        for (int i = threadIdx.x; i < nb; i += blockDim.x) lcnt[i] = 0u;
        __syncthreads();
        const unsigned i64 = flags[1];
        const int chunk = (n_edges + NBIN - 1) / NBIN;
        const int e0 = blockIdx.x * chunk;
        const int e1 = min(e0 + chunk, n_edges);
        for (int e = e0 + threadIdx.x; e < e1; e += blockDim.x) {
            int s, d;
            if (i64) {
                s = (int)((const long long*)srcp)[e];
                d = (int)((const long long*)dstp)[e];
            } else {
                s = ((const int*)srcp)[e];
                d = ((const int*)dstp)[e];
            }
            const int bkt = d >> 6;
            const unsigned pk = ((unsigned)(d & 63) << 26) | (unsigned)s;
            unsigned pos = atomicAdd(&lcnt[bkt], 1u);
            if ((int)pos < depth) {
                stage[bkt * depth + (int)pos] = pk;
            } else {
                unsigned g = atomicAdd(&cursor[bkt], 1u);
                binned[g] = pk;
            }
        }
        __syncthreads();
        for (int bkt = threadIdx.x; bkt < nb; bkt += blockDim.x) {
            int k = min((int)lcnt[bkt], depth);
            if (k > 0) {
                unsigned base = atomicAdd(&cursor[bkt], (unsigned)k);
                for (int i = 0; i < k; ++i) binned[base + i] = stage[bkt * depth + i];
            }
        }
    } else {
        // -------------------------- gemm path -----------------------------
        const unsigned f32 = flags[0];
        const int lane = threadIdx.x & 63;
        const int waveInBlk = threadIdx.x >> 6;
        const int wavesPerBlk = blockDim.x >> 6;          // 8
        const int gwave = (blockIdx.x - NBIN) * wavesPerBlk + waveInBlk;
        const int nwaves = NGEMM * wavesPerBlk;
        const int n_rows = 2 * n_nodes;
        const int ngroups = (n_rows + 3) / 4;

        float* ldsb = (float*)lds;                        // 8KB of the dyn LDS
        float* slot = &ldsb[waveInBlk * 4 * NCH];

        float w[NCH];
        float bias;
        if (f32) {
            const float* Wf = (const float*)Wp;
            #pragma unroll
            for (int k = 0; k < NCH; ++k) w[k] = Wf[lane * NCH + k];
            bias = ((const float*)bp)[lane];
        } else {
            const __hip_bfloat16* Wh = (const __hip_bfloat16*)Wp;
            #pragma unroll
            for (int k = 0; k < NCH; ++k) w[k] = __bfloat162float(Wh[lane * NCH + k]);
            bias = __bfloat162float(((const __hip_bfloat16*)bp)[lane]);
        }

        const int niter = (ngroups + nwaves - 1) / nwaves;
        for (int it = 0; it < niter; ++it) {
            const int grp = gwave + it * nwaves;
            const bool gvalid = (grp < ngroups);
            const int m0 = grp * 4;
            if (gvalid) {
                const int myrow = m0 + (lane >> 4);
                const int col = (lane & 15) * 4;
                float x0 = 0.f, x1 = 0.f, x2 = 0.f, x3 = 0.f;
                if (myrow < n_rows) {
                    const bool isQ = (myrow >= n_nodes);
                    const int r = isQ ? (myrow - n_nodes) : myrow;
                    const void* inp = isQ ? Rp : Gp;
                    if (f32) {
                        float4 v = *(const float4*)((const float*)inp +
                                                    (size_t)r * NCH + col);
                        x0 = v.x; x1 = v.y; x2 = v.z; x3 = v.w;
                    } else {
                        ushort4 v = *(const ushort4*)((const unsigned short*)inp +
                                                      (size_t)r * NCH + col);
                        x0 = __bfloat162float(*(__hip_bfloat16*)&v.x);
                        x1 = __bfloat162float(*(__hip_bfloat16*)&v.y);
                        x2 = __bfloat162float(*(__hip_bfloat16*)&v.z);
                        x3 = __bfloat162float(*(__hip_bfloat16*)&v.w);
                    }
                }
                const int sb = (lane >> 4) * NCH + col;
                slot[sb + 0] = x0; slot[sb + 1] = x1;
                slot[sb + 2] = x2; slot[sb + 3] = x3;
            }
            __syncthreads();
            if (gvalid) {
                #pragma unroll
                for (int rr = 0; rr < 4; ++rr) {
                    const int m = m0 + rr;
                    if (m < n_rows) {
                        float a0 = 0.f, a1 = 0.f, a2 = 0.f, a3 = 0.f;
                        const float4* r4 = (const float4*)(slot + rr * NCH);
                        #pragma unroll
                        for (int q = 0; q < 16; ++q) {
                            float4 rv = r4[q];
                            a0 = fmaf(rv.x, w[4 * q + 0], a0);
                            a1 = fmaf(rv.y, w[4 * q + 1], a1);
                            a2 = fmaf(rv.z, w[4 * q + 2], a2);
                            a3 = fmaf(rv.w, w[4 * q + 3], a3);
                        }
                        float acc = (a0 + a1) + (a2 + a3);
                        if (m >= n_nodes) acc -= bias;       // Q' = RSC@W^T - b
                        if (f32) ((float*)PQ)[(size_t)m * NCH + lane] = acc;
                        else ((__hip_bfloat16*)PQ)[(size_t)m * NCH + lane] =
                                 __float2bfloat16(acc);
                    }
                }
            }
            __syncthreads();
        }
    }
}

// ---------------------------------------------------------------------------
// FUSED bucket sort + node aggregation: block = bucket of 64 dst nodes.
// Stage packed edges in LDS, in-LDS counting sort into per-node runs (no
// sorted_src global round-trip), then the proven wave-per-node gather:
// lane = channel, src ids via LDS broadcast, register accumulation (NO LDS
// accumulators — round-1 lesson). LDS 13.3 KB, 8 waves -> 24 waves/CU at
// grid 782. Overflow (>NB_CAP staged) falls back to a per-node filter scan
// over global binned (rare for Poisson lambda~1024).
// ---------------------------------------------------------------------------
__global__ __launch_bounds__(512)
void bucket_node_kernel(const unsigned* __restrict__ binned,
                        const unsigned* __restrict__ boffs,
                        const unsigned* __restrict__ gcnt,
                        const void* __restrict__ PQ,
                        const unsigned* __restrict__ flags,
                        void* __restrict__ outp, int n_nodes) {
    __shared__ unsigned scnt[SPAN];      // staged per-node counts
    __shared__ unsigned soff[SPAN];      // per-node run starts (staged)
    __shared__ unsigned cur[SPAN];
    __shared__ unsigned dext[SPAN];      // overflow per-node counts
    __shared__ unsigned stage[NB_CAP];
    __shared__ unsigned sorted[NB_CAP];

    const int b = blockIdx.x;
    const int tid = threadIdx.x;
    const int estart = (int)boffs[b];
    const int count = (int)gcnt[b];
    const int lim = (count < NB_CAP) ? count : NB_CAP;

    if (tid < SPAN) { scnt[tid] = 0u; dext[tid] = 0u; }
    __syncthreads();

    for (int i = tid; i < count; i += 512) {
        const unsigned pk = binned[estart + i];
        if (i < NB_CAP) { stage[i] = pk; atomicAdd(&scnt[pk >> 26], 1u); }
        else atomicAdd(&dext[pk >> 26], 1u);
    }
    __syncthreads();

    if (tid == 0) {
        unsigned run = 0u;
        #pragma unroll
        for (int i = 0; i < SPAN; ++i) { soff[i] = run; cur[i] = run; run += scnt[i]; }
    }
    __syncthreads();

    for (int i = tid; i < lim; i += 512) {
        const unsigned pk = stage[i];
        const unsigned pos = atomicAdd(&cur[pk >> 26], 1u);
        sorted[pos] = pk & 0x03FFFFFFu;
    }
    __syncthreads();

    // ------------------- node phase: wave per node -------------------------
    const unsigned f32 = flags[0];
    const int lane = tid & 63;
    const int wid = tid >> 6;            // 0..7
    const float* Pf = (const float*)PQ;
    const unsigned short* Ph = (const unsigned short*)PQ;

    for (int nn = wid; nn < SPAN; nn += 8) {
        const int n = b * SPAN + nn;
        if (n >= n_nodes) break;          // nn monotonic -> safe
        float q;
        if (f32) q = Pf[(size_t)(n_nodes + n) * NCH + lane];
        else {
            unsigned short h = Ph[(size_t)(n_nodes + n) * NCH + lane];
            q = __bfloat162float(*(__hip_bfloat16*)&h);
        }
        const int s0i = (int)soff[nn];
        const int scn = (int)scnt[nn];
        float vmax = 0.0f, vsum = 0.0f;
        int j = 0;
        for (; j + 4 <= scn; j += 4) {
            const int e0 = (int)sorted[s0i + j];
            const int e1 = (int)sorted[s0i + j + 1];
            const int e2 = (int)sorted[s0i + j + 2];
            const int e3 = (int)sorted[s0i + j + 3];
            float p0, p1, p2, p3;
            if (f32) {
                p0 = Pf[(size_t)e0 * NCH + lane];
                p1 = Pf[(size_t)e1 * NCH + lane];
                p2 = Pf[(size_t)e2 * NCH + lane];
                p3 = Pf[(size_t)e3 * NCH + lane];
            } else {
                unsigned short h0 = Ph[(size_t)e0 * NCH + lane];
                unsigned short h1 = Ph[(size_t)e1 * NCH + lane];
                unsigned short h2 = Ph[(size_t)e2 * NCH + lane];
                unsigned short h3 = Ph[(size_t)e3 * NCH + lane];
                p0 = __bfloat162float(*(__hip_bfloat16*)&h0);
                p1 = __bfloat162float(*(__hip_bfloat16*)&h1);
                p2 = __bfloat162float(*(__hip_bfloat16*)&h2);
                p3 = __bfloat162float(*(__hip_bfloat16*)&h3);
            }
            const float v0 = fmaxf(p0 - q, 0.0f);
            const float v1 = fmaxf(p1 - q, 0.0f);
            const float v2 = fmaxf(p2 - q, 0.0f);
            const float v3 = fmaxf(p3 - q, 0.0f);
            vmax = fmaxf(fmaxf(vmax, v0), fmaxf(v1, fmaxf(v2, v3)));
            vsum += (v0 + v1) + (v2 + v3);
        }
        for (; j < scn; ++j) {
            const int e = (int)sorted[s0i + j];
            float p;
            if (f32) p = Pf[(size_t)e * NCH + lane];
            else {
                unsigned short h = Ph[(size_t)e * NCH + lane];
                p = __bfloat162float(*(__hip_bfloat16*)&h);
            }
            const float v = fmaxf(p - q, 0.0f);
            vmax = fmaxf(vmax, v);
            vsum += v;
        }
        // overflow tail (count > NB_CAP): filter scan over global binned.
        for (int i = NB_CAP; i < count; ++i) {
            const unsigned pk = binned[estart + i];     // wave-uniform load
            if ((int)(pk >> 26) == nn) {
                const int e = (int)(pk & 0x03FFFFFFu);
                float p;
                if (f32) p = Pf[(size_t)e * NCH + lane];
                else {
                    unsigned short h = Ph[(size_t)e * NCH + lane];
                    p = __bfloat162float(*(__hip_bfloat16*)&h);
                }
                const float v = fmaxf(p - q, 0.0f);
                vmax = fmaxf(vmax, v);
                vsum += v;
            }
        }
        const int deg = scn + (int)dext[nn];
        const float avg = vsum / (float)(deg > 0 ? deg : 1);
        if (f32) {
            float* out = (float*)outp;
            out[(size_t)n * 2 * NCH + lane] = vmax;
            out[(size_t)n * 2 * NCH + NCH + lane] = avg;
        } else {
            __hip_bfloat16* out = (__hip_bfloat16*)outp;
            out[(size_t)n * 2 * NCH + lane] = __float2bfloat16(vmax);
            out[(size_t)n * 2 * NCH + NCH + lane] = __float2bfloat16(avg);
        }
    }
}

extern "C" void kernel_launch(void* const* d_in, const int* in_sizes, int n_in,
                              void* d_out, int out_size, void* d_ws, size_t ws_size,
                              hipStream_t stream) {
    const void* G = d_in[0];
    const void* RSC = d_in[1];
    const void* src = d_in[2];
    const void* dst = d_in[3];
    const void* W = d_in[4];
    const void* b = d_in[5];

    const int n_nodes = in_sizes[0] / NCH;
    const int n_edges = in_sizes[2];
    const int nb = (n_nodes + SPAN - 1) / SPAN;

    // ws layout (bytes): [flags 256][binned 4E][boffs 4nb][cursor 4nb]
    //                    [gcnt 4nb][PQ dtype*64*2N]
    char* ws = (char*)d_ws;
    unsigned* flags = (unsigned*)ws;
    size_t off = 256;
    unsigned* binned = (unsigned*)(ws + off);
    off += (((size_t)n_edges * 4 + 255) / 256) * 256;
    unsigned* boffs = (unsigned*)(ws + off);
    off += (((size_t)nb * 4 + 255) / 256) * 256;
    unsigned* cursor = (unsigned*)(ws + off);
    off += (((size_t)nb * 4 + 255) / 256) * 256;
    unsigned* gcnt = (unsigned*)(ws + off);
    off += (((size_t)nb * 4 + 255) / 256) * 256;
    void* PQ = (void*)(ws + off);                   // fp32 or bf16 per flags[0]

    const int n_g_probe = (in_sizes[0] < 8192) ? in_sizes[0] : 8192;
    const int n_idx_probe = (n_edges < 8192) ? n_edges : 8192;

    detect_init_kernel<<<64, 256, 0, stream>>>((const unsigned short*)G, n_g_probe,
                                               (const unsigned*)src, n_idx_probe,
                                               flags, gcnt, nb);

    bucket_hist_kernel<<<HIST_BLOCKS, HIST_THREADS, (size_t)nb * 4, stream>>>(
        dst, gcnt, flags, n_edges, nb);

    bucket_scan_kernel<<<1, 1024, 0, stream>>>(gcnt, boffs, cursor, nb);

    // depth sized for ~37.5K LDS. Per binning block the expected bucket fill
    // is ~n_edges/NBIN/nb (~4); P(>11) ~ 0.1%.
    int depth = 9728 / nb - 1;
    if (depth > 19) depth = 19;
    if (depth < 4) depth = 4;
    size_t bin_lds = (size_t)nb * (depth + 1) * 4;
    const size_t gemm_lds = (size_t)(FUSE_THREADS / 64) * 4 * NCH * 4;  // 8 KB
    if (bin_lds < gemm_lds) bin_lds = gemm_lds;

    binning_gemm_kernel<<<NBIN + NGEMM, FUSE_THREADS, bin_lds, stream>>>(
        src, dst, cursor, binned, flags, n_edges, nb, depth,
        G, RSC, W, b, PQ, n_nodes);

    bucket_node_kernel<<<nb, 512, 0, stream>>>(binned, boffs, gcnt, PQ, flags,
                                               d_out, n_nodes);
}